// Round 8
// baseline (40.268 us; speedup 1.0000x reference)
//
#include <hip/hip_runtime.h>
#include <math.h>

#define NPTS 16384
#define DIM  24
#define KPAD 32
#define ESIG 65536
#define ERND 32768
#define THRESH 2.0f
#define NTI   256        // 64-row tiles
#define NIDS  32896      // NTI*(NTI+1)/2 upper-triangle wave-tiles
#define NWAVE 4096       // 512 blocks * 8 waves

typedef __attribute__((ext_vector_type(8))) short bf16x8;
typedef __attribute__((ext_vector_type(4))) float f32x4;

// ws layout: ushort Ab[16384*32]; ushort Bb[16384*32]

__device__ __forceinline__ unsigned short f2bf(float x) {
    unsigned int u = __float_as_uint(x);
    unsigned int r = u + 0x7fffu + ((u >> 16) & 1u);
    return (unsigned short)(r >> 16);
}

__device__ __forceinline__ float min3f(float a, float b, float c) {
    return fminf(fminf(a, b), c);   // fuses to v_min3_f32
}

__device__ __forceinline__ float wave_reduce(float v) {
#pragma unroll
    for (int off = 32; off > 0; off >>= 1)
        v += __shfl_down(v, off, 64);
    return v;
}

__device__ __forceinline__ float block_reduce256(float v) {
    __shared__ float red[4];
    int lane = threadIdx.x & 63;
    int wid  = threadIdx.x >> 6;
    v = wave_reduce(v);
    if (lane == 0) red[wid] = v;
    __syncthreads();
    float s = 0.f;
    if (threadIdx.x == 0) s = red[0] + red[1] + red[2] + red[3];
    return s;
}

__device__ __forceinline__ float edge_d2(const float* __restrict__ emb, int a, int b) {
    const float4* ra = reinterpret_cast<const float4*>(emb + (size_t)a * DIM);
    const float4* rb = reinterpret_cast<const float4*>(emb + (size_t)b * DIM);
    float d2 = 0.f;
#pragma unroll
    for (int k = 0; k < 6; ++k) {
        float4 va = ra[k], vb = rb[k];
        float dx = va.x - vb.x, dy = va.y - vb.y;
        float dz = va.z - vb.z, dw = va.w - vb.w;
        d2 += dx * dx; d2 += dy * dy; d2 += dz * dz; d2 += dw * dw;
    }
    return d2;
}

// blocks [0,64): prep Ab/Bb; [64,320): signal edges; [320,448): random edges
__global__ __launch_bounds__(256) void fused_pre_kernel(
    const float* __restrict__ emb, const int* __restrict__ sedge,
    const int* __restrict__ redge, const int* __restrict__ pid,
    unsigned short* __restrict__ Ab, unsigned short* __restrict__ Bb,
    float* __restrict__ out)
{
    int b = blockIdx.x, t = threadIdx.x;
    if (b < 64) {
        int i = b * 256 + t;
        const float4* rp = reinterpret_cast<const float4*>(emb + (size_t)i * DIM);
        float v[24];
        float s = 0.f;
#pragma unroll
        for (int k = 0; k < 6; ++k) {
            float4 q = rp[k];
            v[4*k+0] = q.x; v[4*k+1] = q.y; v[4*k+2] = q.z; v[4*k+3] = q.w;
            s += q.x*q.x + q.y*q.y + q.z*q.z + q.w*q.w;
        }
        union { unsigned short u[32]; int4 q[4]; } a, bb;
#pragma unroll
        for (int k = 0; k < 24; ++k) { a.u[k] = f2bf(-2.f * v[k]); bb.u[k] = f2bf(v[k]); }
        a.u[24] = f2bf(s);   a.u[25] = f2bf(1.f);
        bb.u[24] = f2bf(1.f); bb.u[25] = f2bf(s);
#pragma unroll
        for (int k = 26; k < 32; ++k) { a.u[k] = 0; bb.u[k] = 0; }
        int4* pa = reinterpret_cast<int4*>(Ab + (size_t)i * KPAD);
        int4* pb = reinterpret_cast<int4*>(Bb + (size_t)i * KPAD);
#pragma unroll
        for (int k = 0; k < 4; ++k) { pa[k] = a.q[k]; pb[k] = bb.q[k]; }
    } else if (b < 320) {
        int e = (b - 64) * 256 + t;
        float d2 = edge_d2(emb, sedge[e], sedge[ESIG + e]) + 1e-12f;
        float s = block_reduce256(d2);
        if (t == 0) atomicAdd(out, s * (1.f / ESIG));
    } else {
        int e = (b - 320) * 256 + t;
        int a = redge[e], bj = redge[ERND + e];
        float val = 0.f;
        if (pid[a] != pid[bj]) {
            float d = sqrtf(edge_d2(emb, a, bj) + 1e-12f);
            float h = 1.f - d;
            if (h > 0.f) val = h * h;
        }
        float s = block_reduce256(val);
        if (t == 0) atomicAdd(out, s * (1.f / ERND));
    }
}

// Per-wave 64x64 tiles over the exact ti<=tj triangle, contiguous-id runs.
// No LDS, no barriers. A-fragments reused across a run; B streamed from L2.
__global__ __launch_bounds__(512) void knn_wave_kernel(
    const unsigned short* __restrict__ Ab, const unsigned short* __restrict__ Bb,
    const float* __restrict__ emb, const int* __restrict__ pid,
    float* __restrict__ out)
{
    const int gw   = blockIdx.x * 8 + (threadIdx.x >> 6);   // 0..4095
    const int lane = threadIdx.x & 63;
    const int lrow = lane & 15, lkb = (lane >> 4) * 8;

    // contiguous run: first 128 waves take 9 ids, rest 8  (128*9 + 3968*8 = 32896)
    int start = gw * 8 + (gw < 128 ? gw : 128);
    int todo  = 8 + (gw < 128 ? 1 : 0);

    // decode start -> (ti, tj):  C(t) = t*(513-t)/2, tj = ti + (start - C(ti))
    int ti = (int)((513.0f - sqrtf(263169.0f - 8.0f * (float)start)) * 0.5f);
    while (ti * (513 - ti) / 2 > start) --ti;
    while ((ti + 1) * (513 - (ti + 1)) / 2 <= start) ++ti;
    int tj = ti + (start - ti * (513 - ti) / 2);

    const f32x4 zero = {0.f, 0.f, 0.f, 0.f};
    float lacc = 0.f;

    while (todo > 0) {
        // A fragments for current ti (reused while ti unchanged)
        const int i0 = ti * 64;
        bf16x8 af[4];
#pragma unroll
        for (int r = 0; r < 4; ++r)
            af[r] = *reinterpret_cast<const bf16x8*>(
                Ab + (size_t)(i0 + r * 16 + lrow) * KPAD + lkb);

        do {
            const int j0 = tj * 64;
            bf16x8 bfr[4];
#pragma unroll
            for (int c = 0; c < 4; ++c)
                bfr[c] = *reinterpret_cast<const bf16x8*>(
                    Bb + (size_t)(j0 + c * 16 + lrow) * KPAD + lkb);

            f32x4 acc[4][4];
#pragma unroll
            for (int r = 0; r < 4; ++r)
#pragma unroll
                for (int c = 0; c < 4; ++c)
                    acc[r][c] = __builtin_amdgcn_mfma_f32_16x16x32_bf16(af[r], bfr[c], zero, 0, 0, 0);

            float tm[16];
#pragma unroll
            for (int r = 0; r < 4; ++r)
#pragma unroll
                for (int c = 0; c < 4; ++c)
                    tm[r * 4 + c] = fminf(min3f(acc[r][c][0], acc[r][c][1], acc[r][c][2]),
                                          acc[r][c][3]);
            float m0 = min3f(tm[0], tm[1], tm[2]);
            float m1 = min3f(tm[3], tm[4], tm[5]);
            float m2 = min3f(tm[6], tm[7], tm[8]);
            float m3 = min3f(tm[9], tm[10], tm[11]);
            float m4 = min3f(tm[12], tm[13], tm[14]);
            float mn = fminf(min3f(min3f(m0, m1, m2), m3, m4), tm[15]);

            if (mn < THRESH) {   // diagonal tiles / true near-pairs only
#pragma unroll
                for (int r = 0; r < 4; ++r)
#pragma unroll
                    for (int c = 0; c < 4; ++c)
#pragma unroll
                        for (int e = 0; e < 4; ++e) {
                            if (acc[r][c][e] < THRESH) {
                                int i = i0 + r * 16 + (lane >> 4) * 4 + e;
                                int j = j0 + c * 16 + (lane & 15);
                                if (i < j && pid[i] != pid[j]) {
                                    float d = sqrtf(fmaxf(edge_d2(emb, i, j), 0.f) + 1e-12f);
                                    if (d < 1.f) { float h = 1.f - d; lacc += h * h; }
                                }
                            }
                        }
            }

            ++tj; --todo;
        } while (todo > 0 && tj < NTI);

        if (tj == NTI) { ++ti; tj = ti; }
    }

    if (__any(lacc != 0.f)) {
        float wsum = wave_reduce(lacc);
        if (lane == 0) atomicAdd(out, wsum * (2.f / NPTS));
    }
}

extern "C" void kernel_launch(void* const* d_in, const int* in_sizes, int n_in,
                              void* d_out, int out_size, void* d_ws, size_t ws_size,
                              hipStream_t stream) {
    const float* emb   = (const float*)d_in[0];
    const int*   sedge = (const int*)d_in[1];
    const int*   redge = (const int*)d_in[2];
    const int*   pid   = (const int*)d_in[3];
    float* out = (float*)d_out;

    unsigned short* Ab = (unsigned short*)d_ws;               // 16384*32
    unsigned short* Bb = Ab + (size_t)NPTS * KPAD;            // 16384*32

    hipMemsetAsync(out, 0, sizeof(float), stream);
    fused_pre_kernel<<<448, 256, 0, stream>>>(emb, sedge, redge, pid, Ab, Bb, out);
    knn_wave_kernel<<<512, 512, 0, stream>>>(Ab, Bb, emb, pid, out);
}

// Round 9
// 30.892 us; speedup vs baseline: 1.3035x; 1.3035x over previous
//
#include <hip/hip_runtime.h>
#include <math.h>

#define NPTS 16384
#define DIM  24
#define ESIG 65536
#define ERND 32768
#define THRESH 2.0f
#define LDSS 40      // LDS row stride in shorts (80 B, 16B-aligned for b128 ops)
#define NBLK 4160    // triangular knn block count: sum_{bi<64}(128-2*bi)
#define EBLK 192     // 128 signal + 64 random edge blocks

typedef __attribute__((ext_vector_type(8))) short bf16x8;
typedef __attribute__((ext_vector_type(4))) float f32x4;

__device__ __forceinline__ unsigned short f2bf(float x) {
    unsigned int u = __float_as_uint(x);
    unsigned int r = u + 0x7fffu + ((u >> 16) & 1u);
    return (unsigned short)(r >> 16);
}

__device__ __forceinline__ float min3f(float a, float b, float c) {
    return fminf(fminf(a, b), c);   // fuses to v_min3_f32
}

__device__ __forceinline__ float wave_reduce(float v) {
#pragma unroll
    for (int off = 32; off > 0; off >>= 1)
        v += __shfl_down(v, off, 64);
    return v;
}

__device__ __forceinline__ float edge_d2(const float* __restrict__ emb, int a, int b) {
    const float4* ra = reinterpret_cast<const float4*>(emb + (size_t)a * DIM);
    const float4* rb = reinterpret_cast<const float4*>(emb + (size_t)b * DIM);
    float d2 = 0.f;
#pragma unroll
    for (int k = 0; k < 6; ++k) {
        float4 va = ra[k], vb = rb[k];
        float dx = va.x - vb.x, dy = va.y - vb.y;
        float dz = va.z - vb.z, dw = va.w - vb.w;
        d2 += dx * dx; d2 += dy * dy; d2 += dz * dz; d2 += dw * dw;
    }
    return d2;
}

// ONE kernel, grid = EBLK + NBLK, 512 threads.
// blocks [0,128): signal edges; [128,192): random edges; [192, 192+4160): knn tiles.
__global__ __launch_bounds__(512) void fused_kernel(
    const float* __restrict__ emb, const int* __restrict__ sedge,
    const int* __restrict__ redge, const int* __restrict__ pid,
    float* __restrict__ out)
{
    __shared__ short lA[256 * LDSS];
    __shared__ short lB[128 * LDSS];
    __shared__ float red[8];

    const int b = blockIdx.x, t = threadIdx.x;
    const int lane = t & 63, wid = t >> 6;

    if (b < EBLK) {
        // ---------------- edge blocks ----------------
        float val;
        if (b < 128) {
            int e = b * 512 + t;
            val = edge_d2(emb, sedge[e], sedge[ESIG + e]) + 1e-12f;
            val *= (1.f / ESIG);
        } else {
            int e = (b - 128) * 512 + t;
            int a = redge[e], bj = redge[ERND + e];
            val = 0.f;
            if (pid[a] != pid[bj]) {
                float d = sqrtf(edge_d2(emb, a, bj) + 1e-12f);
                float h = 1.f - d;
                if (h > 0.f) val = h * h * (1.f / ERND);
            }
        }
        float w = wave_reduce(val);
        if (lane == 0) red[wid] = w;
        __syncthreads();
        if (t == 0) {
            float s = red[0] + red[1] + red[2] + red[3]
                    + red[4] + red[5] + red[6] + red[7];
            atomicAdd(out, s);
        }
        return;
    }

    // ---------------- knn tile block ----------------
    // decode compact id -> (bi, bj): C(bi) = bi*(129-bi), bj = 2*bi + (id - C(bi))
    const int id = b - EBLK;
    int bi = (int)((129.0f - sqrtf(16641.0f - 4.0f * (float)id)) * 0.5f);
    while (bi * (129 - bi) > id) --bi;
    while ((bi + 1) * (129 - (bi + 1)) <= id) ++bi;
    const int bj = 2 * bi + (id - bi * (129 - bi));
    const int i0 = bi * 256, j0 = bj * 128;

    // stage: threads 0..383 each convert one emb row to an augmented bf16 row.
    //   A row i: [-2*E_i (24), sq_i, 1, 0...]   B row j: [E_j (24), 1, sq_j, 0...]
    //   dot(A_i, B_j) = sq_i + sq_j - 2 E_i.E_j = d^2
    if (t < 384) {
        const bool isA = t < 256;
        const int g = isA ? (i0 + t) : (j0 + t - 256);
        const float4* rp = reinterpret_cast<const float4*>(emb + (size_t)g * DIM);
        float v[24];
        float s = 0.f;
#pragma unroll
        for (int k = 0; k < 6; ++k) {
            float4 q = rp[k];
            v[4*k+0] = q.x; v[4*k+1] = q.y; v[4*k+2] = q.z; v[4*k+3] = q.w;
            s += q.x*q.x + q.y*q.y + q.z*q.z + q.w*q.w;
        }
        union { unsigned short u[32]; int4 q[4]; } rowu;
        const float m = isA ? -2.f : 1.f;
#pragma unroll
        for (int k = 0; k < 24; ++k) rowu.u[k] = f2bf(m * v[k]);
        unsigned short sqb = f2bf(s);
        rowu.u[24] = isA ? sqb : (unsigned short)0x3F80;
        rowu.u[25] = isA ? (unsigned short)0x3F80 : sqb;
#pragma unroll
        for (int k = 26; k < 32; ++k) rowu.u[k] = 0;
        short* dst = isA ? &lA[t * LDSS] : &lB[(t - 256) * LDSS];
#pragma unroll
        for (int k = 0; k < 4; ++k)
            *reinterpret_cast<int4*>(dst + k * 8) = rowu.q[k];
    }
    __syncthreads();

    const int wr = wid >> 1, wc = wid & 1;          // 4x2 wave grid, 64x64 per wave
    const int lrow = lane & 15, lkb = (lane >> 4) * 8;

    bf16x8 af[4], bfr[4];
#pragma unroll
    for (int r = 0; r < 4; ++r)
        af[r] = *reinterpret_cast<const bf16x8*>(
            &lA[(wr * 64 + r * 16 + lrow) * LDSS + lkb]);
#pragma unroll
    for (int c = 0; c < 4; ++c)
        bfr[c] = *reinterpret_cast<const bf16x8*>(
            &lB[(wc * 64 + c * 16 + lrow) * LDSS + lkb]);

    const f32x4 zero = {0.f, 0.f, 0.f, 0.f};
    f32x4 acc[4][4];
#pragma unroll
    for (int r = 0; r < 4; ++r)
#pragma unroll
        for (int c = 0; c < 4; ++c)
            acc[r][c] = __builtin_amdgcn_mfma_f32_16x16x32_bf16(af[r], bfr[c], zero, 0, 0, 0);

    // min over the 64 d^2 values this lane holds (min3 trees)
    float tm[16];
#pragma unroll
    for (int r = 0; r < 4; ++r)
#pragma unroll
        for (int c = 0; c < 4; ++c)
            tm[r * 4 + c] = fminf(min3f(acc[r][c][0], acc[r][c][1], acc[r][c][2]),
                                  acc[r][c][3]);
    float m0 = min3f(tm[0], tm[1], tm[2]);
    float m1 = min3f(tm[3], tm[4], tm[5]);
    float m2 = min3f(tm[6], tm[7], tm[8]);
    float m3 = min3f(tm[9], tm[10], tm[11]);
    float m4 = min3f(tm[12], tm[13], tm[14]);
    float mn = fminf(min3f(min3f(m0, m1, m2), m3, m4), tm[15]);

    float lacc = 0.f;
    if (mn < THRESH) {   // fires only for diagonal tiles / true near-pairs
#pragma unroll
        for (int r = 0; r < 4; ++r)
#pragma unroll
            for (int c = 0; c < 4; ++c)
#pragma unroll
                for (int e = 0; e < 4; ++e) {
                    if (acc[r][c][e] < THRESH) {
                        int i = i0 + wr * 64 + r * 16 + (lane >> 4) * 4 + e;
                        int j = j0 + wc * 64 + c * 16 + (lane & 15);
                        if (i < j && pid[i] != pid[j]) {
                            float d = sqrtf(fmaxf(edge_d2(emb, i, j), 0.f) + 1e-12f);
                            if (d < 1.f) { float h = 1.f - d; lacc += h * h; }
                        }
                    }
                }
    }

    if (__any(lacc != 0.f)) {
        float wsum = wave_reduce(lacc);
        if (lane == 0) atomicAdd(out, wsum * (2.f / NPTS));
    }
}

extern "C" void kernel_launch(void* const* d_in, const int* in_sizes, int n_in,
                              void* d_out, int out_size, void* d_ws, size_t ws_size,
                              hipStream_t stream) {
    const float* emb   = (const float*)d_in[0];
    const int*   sedge = (const int*)d_in[1];
    const int*   redge = (const int*)d_in[2];
    const int*   pid   = (const int*)d_in[3];
    float* out = (float*)d_out;

    hipMemsetAsync(out, 0, sizeof(float), stream);
    fused_kernel<<<EBLK + NBLK, 512, 0, stream>>>(emb, sedge, redge, pid, out);
}